// Round 9
// baseline (77007.196 us; speedup 1.0000x reference)
//
#include <hip/hip_runtime.h>
#include <stdint.h>

typedef unsigned long long u64;
typedef uint32_t u32;

#define NPTS 50000
#define MCL  8334          // ceil(50000/6)
#define NITER 8333         // FPS steps after seed
#define OUTC 128
#define WPW  3136          // points per wave (64 lanes * 49)
#define PTT  49            // points per lane
#define MDR  16            // md slots in registers
#define MDL  33            // md slots in LDS (MDR+MDL == PTT)
#define MDS  33            // LDS md stride (gcd(33,32)=1 -> conflict-free)
#define NPAD (1024 * PTT)  // 50176
#define KCH 4              // knn N-chunks
#define CPTS 12500         // points per chunk
#define KTILE 250
#define NTILE 50
#define QBLK 33            // ceil(MCL/256)
#define RB 782             // ceil(NPTS/64) row-blocks for stats
#define NCELL 4096         // 16^3 Morton cells

// ---- ws byte offsets (total ~4.84 MB) ----
#define WS_IDS   0u            // 8448 i32
#define WS_BBOX  33792u        // 8 f32 (min xyz, scale xyz)
#define WS_POSF4 33824u        // 50000 float4 (orig order, w=||p||^2)  -> for KNN
#define WS_SPOS  833824u       // 50176 float4 (sorted, w=orig idx bits) -> for FPS
#define WS_CAND  1636640u      // 8334*32 u64
#define WS_COL   3770144u      // 8334*8 i32
#define WS_PSUM  4036832u      // 782*128 f32
#define WS_PSQ   4437216u      // 782*128 f32
#define WS_AB    4837600u      // alpha[128], beta[128]
#define WS_TOTAL 4838624u

#define OUT_POS   (MCL * OUTC)            // 1066752
#define OUT_BATCH (OUT_POS + MCL * 3)     // 1091754

// pack pos + precomputed ||p||^2 (exact np order: (x*x+y*y)+z*z, no FMA)
__global__ void k_prep(const float* __restrict__ pos, float4* __restrict__ posf4) {
    int i = blockIdx.x * blockDim.x + threadIdx.x;
    if (i < NPTS) {
        float x = pos[3 * i], y = pos[3 * i + 1], z = pos[3 * i + 2];
        float pp = __fadd_rn(__fadd_rn(__fmul_rn(x, x), __fmul_rn(y, y)), __fmul_rn(z, z));
        posf4[i] = make_float4(x, y, z, pp);
    }
}

// global bbox -> min + scale (perf-only; any grouping is exact)
__global__ void __launch_bounds__(1024) k_bbox(const float* __restrict__ pos,
                                               float* __restrict__ bbox) {
    __shared__ float red[16][6];
    const int tid = threadIdx.x, lane = tid & 63, wid = tid >> 6;
    float mnx = 3.4e38f, mny = 3.4e38f, mnz = 3.4e38f;
    float mxx = -3.4e38f, mxy = -3.4e38f, mxz = -3.4e38f;
    for (int i = tid; i < NPTS; i += 1024) {
        float x = pos[3 * i], y = pos[3 * i + 1], z = pos[3 * i + 2];
        mnx = fminf(mnx, x); mxx = fmaxf(mxx, x);
        mny = fminf(mny, y); mxy = fmaxf(mxy, y);
        mnz = fminf(mnz, z); mxz = fmaxf(mxz, z);
    }
    #pragma unroll
    for (int o = 32; o >= 1; o >>= 1) {
        mnx = fminf(mnx, __shfl_xor(mnx, o)); mxx = fmaxf(mxx, __shfl_xor(mxx, o));
        mny = fminf(mny, __shfl_xor(mny, o)); mxy = fmaxf(mxy, __shfl_xor(mxy, o));
        mnz = fminf(mnz, __shfl_xor(mnz, o)); mxz = fmaxf(mxz, __shfl_xor(mxz, o));
    }
    if (lane == 0) {
        red[wid][0] = mnx; red[wid][1] = mny; red[wid][2] = mnz;
        red[wid][3] = mxx; red[wid][4] = mxy; red[wid][5] = mxz;
    }
    __syncthreads();
    if (tid == 0) {
        for (int w2 = 1; w2 < 16; ++w2) {
            red[0][0] = fminf(red[0][0], red[w2][0]);
            red[0][1] = fminf(red[0][1], red[w2][1]);
            red[0][2] = fminf(red[0][2], red[w2][2]);
            red[0][3] = fmaxf(red[0][3], red[w2][3]);
            red[0][4] = fmaxf(red[0][4], red[w2][4]);
            red[0][5] = fmaxf(red[0][5], red[w2][5]);
        }
        bbox[0] = red[0][0]; bbox[1] = red[0][1]; bbox[2] = red[0][2];
        bbox[3] = 16.0f / (fmaxf(red[0][3] - red[0][0], 1e-20f) * 1.000001f);
        bbox[4] = 16.0f / (fmaxf(red[0][4] - red[0][1], 1e-20f) * 1.000001f);
        bbox[5] = 16.0f / (fmaxf(red[0][5] - red[0][2], 1e-20f) * 1.000001f);
    }
}

__device__ __forceinline__ u32 mort(int cx, int cy, int cz) {
    u32 m = 0;
    #pragma unroll
    for (int b = 0; b < 4; ++b)
        m |= (((cx >> b) & 1) << (3 * b)) | (((cy >> b) & 1) << (3 * b + 1)) |
             (((cz >> b) & 1) << (3 * b + 2));
    return m;
}

__device__ __forceinline__ u32 cell_of(float x, float y, float z, const float* bb) {
    int cx = (int)((x - bb[0]) * bb[3]);
    int cy = (int)((y - bb[1]) * bb[4]);
    int cz = (int)((z - bb[2]) * bb[5]);
    cx = min(15, max(0, cx)); cy = min(15, max(0, cy)); cz = min(15, max(0, cz));
    return mort(cx, cy, cz);
}

// single-block Morton bucket sort: hist -> scan -> scatter (w = orig idx bits).
// Pads [NPTS..NPAD) = clones of the LAST SORTED point (corner of Morton order,
// keeps wave 15's bbox tight) with idx sentinel 0xFFFF (inv16=0): the real
// point always beats its clones on tie-break, so pads can never win argmax,
// and their md tracks the real point's md exactly (no tmax inflation).
__global__ void __launch_bounds__(1024) k_sort(const float* __restrict__ pos,
                                               const float* __restrict__ bbox,
                                               float4* __restrict__ spos) {
    __shared__ u32 hist[NCELL];
    __shared__ u32 wsum[16];
    const int tid = threadIdx.x, lane = tid & 63, wid = tid >> 6;
    float bb[6];
    #pragma unroll
    for (int j = 0; j < 6; ++j) bb[j] = bbox[j];
    for (int i = tid; i < NCELL; i += 1024) hist[i] = 0u;
    __syncthreads();
    for (int i = tid; i < NPTS; i += 1024) {
        float x = pos[3 * i], y = pos[3 * i + 1], z = pos[3 * i + 2];
        atomicAdd(&hist[cell_of(x, y, z, bb)], 1u);
    }
    __syncthreads();
    u32 h0 = hist[tid * 4], h1 = hist[tid * 4 + 1], h2 = hist[tid * 4 + 2], h3 = hist[tid * 4 + 3];
    u32 ts = h0 + h1 + h2 + h3;
    u32 sc = ts;
    #pragma unroll
    for (int o = 1; o < 64; o <<= 1) { u32 n = __shfl_up(sc, o); if (lane >= o) sc += n; }
    if (lane == 63) wsum[wid] = sc;
    __syncthreads();
    u32 woff = 0;
    for (int w2 = 0; w2 < wid; ++w2) woff += wsum[w2];
    u32 excl = woff + sc - ts;
    hist[tid * 4 + 0] = excl;
    hist[tid * 4 + 1] = excl + h0;
    hist[tid * 4 + 2] = excl + h0 + h1;
    hist[tid * 4 + 3] = excl + h0 + h1 + h2;
    __syncthreads();
    for (int i = tid; i < NPTS; i += 1024) {
        float x = pos[3 * i], y = pos[3 * i + 1], z = pos[3 * i + 2];
        u32 dst = atomicAdd(&hist[cell_of(x, y, z, bb)], 1u);
        spos[dst] = make_float4(x, y, z, __uint_as_float((u32)i));
    }
    __syncthreads();
    if (tid < NPAD - NPTS) {
        float4 lastp = spos[NPTS - 1];
        lastp.w = __uint_as_float(0xFFFFu);
        spos[NPTS + tid] = lastp;
    }
}

// Exact FPS v5: single block, WAVE-uniform bbox skip (v4 lesson: per-lane skip
// never engages because the wave executes if ANY lane is active), md split
// 16 regs + 33 LDS (spill-proof at the 64-VGPR cap the compiler insists on).
// Lane ownership interleaved (point = wbase + j*64 + lane) -> coalesced loads.
// Skip: lb*(1-1e-6) >= wtmax (wave max md) => provably no md in wave changes
// => all cached per-lane keys stay exact. All skip inputs are wave-uniform.
// key = (md_bits<<32)|(0xFFFF-idx): u64-max == first-index argmax (jnp.argmax).
__global__ void __launch_bounds__(1024) k_fps5(const float4* __restrict__ spos,
                                               const float* __restrict__ pos,
                                               int* __restrict__ ids) {
    const int tid = threadIdx.x, lane = tid & 63, wid = tid >> 6;
    const int wbase = wid * WPW;
    __shared__ float lmd[1024 * MDS];       // 135168 B
    __shared__ u64 keys[1024];              // 8192 B
    __shared__ float px[1024], py[1024], pz[1024];  // 12288 B
    __shared__ float cs[4];
    float md_r[MDR];
    float bxn = 3.4e38f, byn = 3.4e38f, bzn = 3.4e38f;
    float bxm = -3.4e38f, bym = -3.4e38f, bzm = -3.4e38f;
    #pragma unroll
    for (int j = 0; j < MDR; ++j) {
        md_r[j] = 1e10f;
        float4 s = spos[wbase + j * 64 + lane];
        bxn = fminf(bxn, s.x); bxm = fmaxf(bxm, s.x);
        byn = fminf(byn, s.y); bym = fmaxf(bym, s.y);
        bzn = fminf(bzn, s.z); bzm = fmaxf(bzm, s.z);
    }
    #pragma unroll
    for (int j = 0; j < MDL; ++j) {
        lmd[tid * MDS + j] = 1e10f;
        float4 s = spos[wbase + (MDR + j) * 64 + lane];
        bxn = fminf(bxn, s.x); bxm = fmaxf(bxm, s.x);
        byn = fminf(byn, s.y); bym = fmaxf(bym, s.y);
        bzn = fminf(bzn, s.z); bzm = fmaxf(bzm, s.z);
    }
    // wave bbox (uniform across lanes after reduce)
    #pragma unroll
    for (int o = 32; o >= 1; o >>= 1) {
        bxn = fminf(bxn, __shfl_xor(bxn, o)); bxm = fmaxf(bxm, __shfl_xor(bxm, o));
        byn = fminf(byn, __shfl_xor(byn, o)); bym = fmaxf(bym, __shfl_xor(bym, o));
        bzn = fminf(bzn, __shfl_xor(bzn, o)); bzm = fmaxf(bzm, __shfl_xor(bzm, o));
    }
    float wtmax = 1e10f;                    // force first scan
    float cx = pos[0], cy = pos[1], cz = pos[2];   // seed: original point 0
    if (tid == 0) ids[0] = 0;
    for (int it = 0; it < NITER; ++it) {
        float ddx = fmaxf(0.0f, fmaxf(bxn - cx, cx - bxm));
        float ddy = fmaxf(0.0f, fmaxf(byn - cy, cy - bym));
        float ddz = fmaxf(0.0f, fmaxf(bzn - cz, cz - bzm));
        float lb = (ddx * ddx + ddy * ddy + ddz * ddz) * 0.999999f;
        if (lb < wtmax) {                   // wave-uniform branch
            u64 nk = 0ull;
            float bx = 0.f, by = 0.f, bz = 0.f, tml = 0.0f;
            #pragma unroll
            for (int j = 0; j < MDR; ++j) {
                float4 s = spos[wbase + j * 64 + lane];
                float dx = __fsub_rn(s.x, cx), dy = __fsub_rn(s.y, cy), dz = __fsub_rn(s.z, cz);
                float d = __fadd_rn(__fadd_rn(__fmul_rn(dx, dx), __fmul_rn(dy, dy)),
                                    __fmul_rn(dz, dz));
                float m = fminf(md_r[j], d);
                md_r[j] = m;
                tml = fmaxf(tml, m);
                u64 k = ((u64)__float_as_uint(m) << 32) |
                        (u64)(0xFFFFu - (u32)__float_as_uint(s.w));
                if (k > nk) { nk = k; bx = s.x; by = s.y; bz = s.z; }
            }
            #pragma unroll
            for (int j = 0; j < MDL; ++j) {
                float4 s = spos[wbase + (MDR + j) * 64 + lane];
                float dx = __fsub_rn(s.x, cx), dy = __fsub_rn(s.y, cy), dz = __fsub_rn(s.z, cz);
                float d = __fadd_rn(__fadd_rn(__fmul_rn(dx, dx), __fmul_rn(dy, dy)),
                                    __fmul_rn(dz, dz));
                float m = fminf(lmd[tid * MDS + j], d);
                lmd[tid * MDS + j] = m;
                tml = fmaxf(tml, m);
                u64 k = ((u64)__float_as_uint(m) << 32) |
                        (u64)(0xFFFFu - (u32)__float_as_uint(s.w));
                if (k > nk) { nk = k; bx = s.x; by = s.y; bz = s.z; }
            }
            keys[tid] = nk;
            px[tid] = bx; py[tid] = by; pz[tid] = bz;
            #pragma unroll
            for (int o = 32; o >= 1; o >>= 1) tml = fmaxf(tml, __shfl_xor(tml, o));
            wtmax = tml;                    // uniform again
        }
        __syncthreads();
        // Phase B: wave 0 only; carry (key, tid) through the reduce
        if (wid == 0) {
            u64 v = 0ull; int vt = 0;
            #pragma unroll
            for (int j = 0; j < 16; ++j) {
                int t2 = j * 64 + lane;
                u64 k = keys[t2];
                if (k > v) { v = k; vt = t2; }
            }
            #pragma unroll
            for (int o = 32; o >= 1; o >>= 1) {
                u64 ov = __shfl_xor(v, o);
                int ot = __shfl_xor(vt, o);
                if (ov > v) { v = ov; vt = ot; }
            }
            if (lane == 0) {
                ids[it + 1] = 0xFFFF - (int)(v & 0xFFFFull);
                cs[0] = px[vt]; cs[1] = py[vt]; cs[2] = pz[vt];
            }
        }
        __syncthreads();
        cx = cs[0]; cy = cs[1]; cz = cs[2];
    }
}

// sub_pos + sub_batch outputs
__global__ void k_subs(const float* __restrict__ pos, const int* __restrict__ batch,
                       const int* __restrict__ ids, float* __restrict__ out) {
    int m = blockIdx.x * blockDim.x + threadIdx.x;
    if (m < MCL) {
        int id = ids[m];
        out[OUT_POS + m * 3 + 0] = pos[id * 3 + 0];
        out[OUT_POS + m * 3 + 1] = pos[id * 3 + 1];
        out[OUT_POS + m * 3 + 2] = pos[id * 3 + 2];
        out[OUT_BATCH + m] = (float)batch[id];  // zeros in this problem
    }
}

__device__ __forceinline__ u32 f2sort(float d) {
    u32 u = __float_as_uint(d);
    return (u & 0x80000000u) ? ~u : (u | 0x80000000u);
}

// per-(query-block, chunk) partial top-8 by (d, idx) lex key
__global__ void __launch_bounds__(256) k_knn(const float4* __restrict__ posf4,
                                             const int* __restrict__ ids,
                                             u64* __restrict__ cand) {
    __shared__ float4 tile[KTILE];
    const int bid = blockIdx.x, tid = threadIdx.x;
    const int qb = bid % QBLK, chunk = bid / QBLK;
    const int q = qb * 256 + tid;
    const bool act = q < MCL;
    float qx = 0.f, qy = 0.f, qz = 0.f, qq = 0.f;
    if (act) { float4 p = posf4[ids[q]]; qx = p.x; qy = p.y; qz = p.z; qq = p.w; }
    u64 r[8];
    #pragma unroll
    for (int j = 0; j < 8; ++j) r[j] = ~0ull;
    const int base0 = chunk * CPTS;
    for (int t = 0; t < NTILE; ++t) {
        __syncthreads();
        if (tid < KTILE) tile[tid] = posf4[base0 + t * KTILE + tid];
        __syncthreads();
        if (act) {
            for (int p = 0; p < KTILE; ++p) {
                float4 f = tile[p];
                // BLAS sgemm K=3 rounding: c=rn(qx*px); c=fma(qy,py,c); c=fma(qz,pz,c)
                float c = __fmul_rn(qx, f.x);
                c = fmaf(qy, f.y, c);
                c = fmaf(qz, f.z, c);
                float d = __fadd_rn(__fsub_rn(qq, __fmul_rn(2.0f, c)), f.w);
                u64 key = ((u64)f2sort(d) << 32) | (u32)(base0 + t * KTILE + p);
                if (key < r[7]) {
                    r[7] = key;
                    #pragma unroll
                    for (int jj = 7; jj >= 1; --jj) {
                        if (r[jj] < r[jj - 1]) { u64 tk = r[jj]; r[jj] = r[jj - 1]; r[jj - 1] = tk; }
                    }
                }
            }
        }
    }
    if (act) {
        #pragma unroll
        for (int j = 0; j < 8; ++j) cand[(size_t)q * 32 + chunk * 8 + j] = r[j];
    }
}

__global__ void k_merge(const u64* __restrict__ cand, int* __restrict__ col) {
    int q = blockIdx.x * blockDim.x + threadIdx.x;
    if (q >= MCL) return;
    u64 r[8];
    #pragma unroll
    for (int j = 0; j < 8; ++j) r[j] = ~0ull;
    for (int k = 0; k < 32; ++k) {
        u64 key = cand[(size_t)q * 32 + k];
        if (key < r[7]) {
            r[7] = key;
            #pragma unroll
            for (int jj = 7; jj >= 1; --jj) {
                if (r[jj] < r[jj - 1]) { u64 tk = r[jj]; r[jj] = r[jj - 1]; r[jj - 1] = tk; }
            }
        }
    }
    #pragma unroll
    for (int j = 0; j < 8; ++j) col[q * 8 + j] = (int)(r[j] & 0xFFFFFFFFull);
}

// Linear(64->128) per-channel sum / sumsq partials (64 rows per block)
__global__ void __launch_bounds__(256) k_linstats(const float* __restrict__ x,
                                                  const float* __restrict__ w,
                                                  const float* __restrict__ b,
                                                  float* __restrict__ psum,
                                                  float* __restrict__ psq) {
    __shared__ float xs[64 * 65];
    __shared__ float ws[128 * 65];
    const int bid = blockIdx.x, tid = threadIdx.x;
    const int row0 = bid * 64;
    for (int idx = tid; idx < 64 * 64; idx += 256) {
        int r = idx >> 6, j = idx & 63;
        int gr = row0 + r;
        xs[r * 65 + j] = (gr < NPTS) ? x[gr * 64 + j] : 0.0f;
    }
    for (int idx = tid; idx < 128 * 64; idx += 256) {
        int c = idx >> 6, j = idx & 63;
        ws[c * 65 + j] = w[idx];
    }
    __syncthreads();
    const int ch = tid & 127, grp = tid >> 7;
    const float lb = b[ch];
    float s = 0.f, sq = 0.f;
    for (int rr = 0; rr < 32; ++rr) {
        int r = grp * 32 + rr;
        float acc = lb;
        #pragma unroll 8
        for (int j = 0; j < 64; ++j) acc = fmaf(xs[r * 65 + j], ws[ch * 65 + j], acc);
        if (row0 + r < NPTS) { s += acc; sq = fmaf(acc, acc, sq); }
    }
    __syncthreads();
    float* red = xs;  // reuse
    red[grp * 128 + ch] = s;
    red[256 + grp * 128 + ch] = sq;
    __syncthreads();
    if (grp == 0) {
        psum[bid * 128 + ch] = red[ch] + red[128 + ch];
        psq[bid * 128 + ch] = red[256 + ch] + red[256 + 128 + ch];
    }
}

// mean/var -> per-channel affine (alpha, beta); folds GraphNorm
__global__ void k_finalize(const float* __restrict__ psum, const float* __restrict__ psq,
                           const float* __restrict__ gnw, const float* __restrict__ gnb,
                           const float* __restrict__ gms, float* __restrict__ ab) {
    int ch = threadIdx.x;  // 128 threads
    float s = 0.f, q = 0.f;
    for (int bk = 0; bk < RB; ++bk) { s += psum[bk * 128 + ch]; q += psq[bk * 128 + ch]; }
    float m = s / (float)NPTS;
    float e2 = q / (float)NPTS;
    float msc = gms[ch];
    float mm = msc * m;
    float var = e2 - 2.0f * mm * m + mm * mm;
    float inv = rsqrtf(var + 1e-5f);
    float a = inv * gnw[ch];
    ab[ch] = a;
    ab[128 + ch] = gnb[ch] - mm * a;
}

// recompute h rows for the 8 neighbors, max/min, affine+relu, write out
__global__ void __launch_bounds__(128) k_gather(const float* __restrict__ x,
                                                const float* __restrict__ w,
                                                const float* __restrict__ b,
                                                const int* __restrict__ col,
                                                const float* __restrict__ ab,
                                                float* __restrict__ out) {
    __shared__ float xs[8 * 64];
    __shared__ float ws[128 * 65];
    __shared__ int cl[8];
    const int m = blockIdx.x, tid = threadIdx.x;
    if (tid < 8) cl[tid] = col[m * 8 + tid];
    __syncthreads();
    for (int idx = tid; idx < 512; idx += 128) {
        int r = idx >> 6, j = idx & 63;
        xs[idx] = x[cl[r] * 64 + j];
    }
    for (int idx = tid; idx < 128 * 64; idx += 128) {
        int c = idx >> 6, j = idx & 63;
        ws[c * 65 + j] = w[idx];
    }
    __syncthreads();
    const int ch = tid;
    const float lb = b[ch];
    float hmax = -3.402823466e38f, hmin = 3.402823466e38f;
    #pragma unroll
    for (int r = 0; r < 8; ++r) {
        float acc = lb;
        #pragma unroll 8
        for (int j = 0; j < 64; ++j) acc = fmaf(xs[r * 64 + j], ws[ch * 65 + j], acc);
        hmax = fmaxf(hmax, acc);
        hmin = fminf(hmin, acc);
    }
    float a = ab[ch], be = ab[128 + ch];
    float v = (a >= 0.0f) ? hmax : hmin;   // max/affine commute per sign
    out[m * OUTC + ch] = fmaxf(0.0f, fmaf(a, v, be));
}

extern "C" void kernel_launch(void* const* d_in, const int* in_sizes, int n_in,
                              void* d_out, int out_size, void* d_ws, size_t ws_size,
                              hipStream_t stream) {
    const float* x     = (const float*)d_in[0];
    const float* pos   = (const float*)d_in[1];
    const int*   batch = (const int*)d_in[2];
    const float* lin_w = (const float*)d_in[3];
    const float* lin_b = (const float*)d_in[4];
    const float* gnw   = (const float*)d_in[5];
    const float* gnb   = (const float*)d_in[6];
    const float* gms   = (const float*)d_in[7];
    float* out = (float*)d_out;

    if (ws_size < (size_t)WS_TOTAL) return;  // fail loudly via wrong output

    char* ws = (char*)d_ws;
    int*    ids   = (int*)(ws + WS_IDS);
    float*  bbox  = (float*)(ws + WS_BBOX);
    float4* posf4 = (float4*)(ws + WS_POSF4);
    float4* spos  = (float4*)(ws + WS_SPOS);
    u64*    cand  = (u64*)(ws + WS_CAND);
    int*    col   = (int*)(ws + WS_COL);
    float*  psum  = (float*)(ws + WS_PSUM);
    float*  psq   = (float*)(ws + WS_PSQ);
    float*  ab    = (float*)(ws + WS_AB);

    k_prep<<<196, 256, 0, stream>>>(pos, posf4);
    k_bbox<<<1, 1024, 0, stream>>>(pos, bbox);
    k_sort<<<1, 1024, 0, stream>>>(pos, bbox, spos);
    k_fps5<<<1, 1024, 0, stream>>>(spos, pos, ids);
    k_subs<<<QBLK, 256, 0, stream>>>(pos, batch, ids, out);
    k_knn<<<QBLK * KCH, 256, 0, stream>>>(posf4, ids, cand);
    k_merge<<<QBLK, 256, 0, stream>>>(cand, col);
    k_linstats<<<RB, 256, 0, stream>>>(x, lin_w, lin_b, psum, psq);
    k_finalize<<<1, 128, 0, stream>>>(psum, psq, gnw, gnb, gms, ab);
    k_gather<<<MCL, 128, 0, stream>>>(x, lin_w, lin_b, col, ab, out);
}

// Round 10
// 49092.151 us; speedup vs baseline: 1.5686x; 1.5686x over previous
//
#include <hip/hip_runtime.h>
#include <stdint.h>

typedef unsigned long long u64;
typedef uint32_t u32;

#define NPTS 50000
#define MCL  8334          // ceil(50000/6)
#define NITER 8333         // FPS steps after seed
#define OUTC 128
#define WPW  3136          // points per wave (64 lanes * 49)
#define PTT  49            // points per lane == chunks per wave
#define NCH  49            // chunks per wave (chunk j = 64 consecutive points)
#define MDR  12            // md slots in registers
#define MDL  37            // md slots in LDS (MDR+MDL == PTT)
#define MDS  37            // LDS md stride (gcd(37,32)=1 -> conflict-free)
#define NPAD (1024 * PTT)  // 50176
#define KCH 4              // knn N-chunks
#define CPTS 12500         // points per chunk
#define KTILE 250
#define NTILE 50
#define QBLK 33            // ceil(MCL/256)
#define RB 782             // ceil(NPTS/64) row-blocks for stats
#define NCELL 4096         // 16^3 Morton cells

// ---- ws byte offsets (total ~4.84 MB) ----
#define WS_IDS   0u            // 8448 i32
#define WS_BBOX  33792u        // 8 f32 (min xyz, scale xyz)
#define WS_POSF4 33824u        // 50000 float4 (orig order, w=||p||^2)  -> for KNN
#define WS_SPOS  833824u       // 50176 float4 (sorted, w=orig idx bits) -> for FPS
#define WS_CAND  1636640u      // 8334*32 u64
#define WS_COL   3770144u      // 8334*8 i32
#define WS_PSUM  4036832u      // 782*128 f32
#define WS_PSQ   4437216u      // 782*128 f32
#define WS_AB    4837600u      // alpha[128], beta[128]
#define WS_TOTAL 4838624u

#define OUT_POS   (MCL * OUTC)            // 1066752
#define OUT_BATCH (OUT_POS + MCL * 3)     // 1091754

// pack pos + precomputed ||p||^2 (exact np order: (x*x+y*y)+z*z, no FMA)
__global__ void k_prep(const float* __restrict__ pos, float4* __restrict__ posf4) {
    int i = blockIdx.x * blockDim.x + threadIdx.x;
    if (i < NPTS) {
        float x = pos[3 * i], y = pos[3 * i + 1], z = pos[3 * i + 2];
        float pp = __fadd_rn(__fadd_rn(__fmul_rn(x, x), __fmul_rn(y, y)), __fmul_rn(z, z));
        posf4[i] = make_float4(x, y, z, pp);
    }
}

// global bbox -> min + scale (perf-only; any grouping is exact)
__global__ void __launch_bounds__(1024) k_bbox(const float* __restrict__ pos,
                                               float* __restrict__ bbox) {
    __shared__ float red[16][6];
    const int tid = threadIdx.x, lane = tid & 63, wid = tid >> 6;
    float mnx = 3.4e38f, mny = 3.4e38f, mnz = 3.4e38f;
    float mxx = -3.4e38f, mxy = -3.4e38f, mxz = -3.4e38f;
    for (int i = tid; i < NPTS; i += 1024) {
        float x = pos[3 * i], y = pos[3 * i + 1], z = pos[3 * i + 2];
        mnx = fminf(mnx, x); mxx = fmaxf(mxx, x);
        mny = fminf(mny, y); mxy = fmaxf(mxy, y);
        mnz = fminf(mnz, z); mxz = fmaxf(mxz, z);
    }
    #pragma unroll
    for (int o = 32; o >= 1; o >>= 1) {
        mnx = fminf(mnx, __shfl_xor(mnx, o)); mxx = fmaxf(mxx, __shfl_xor(mxx, o));
        mny = fminf(mny, __shfl_xor(mny, o)); mxy = fmaxf(mxy, __shfl_xor(mxy, o));
        mnz = fminf(mnz, __shfl_xor(mnz, o)); mxz = fmaxf(mxz, __shfl_xor(mxz, o));
    }
    if (lane == 0) {
        red[wid][0] = mnx; red[wid][1] = mny; red[wid][2] = mnz;
        red[wid][3] = mxx; red[wid][4] = mxy; red[wid][5] = mxz;
    }
    __syncthreads();
    if (tid == 0) {
        for (int w2 = 1; w2 < 16; ++w2) {
            red[0][0] = fminf(red[0][0], red[w2][0]);
            red[0][1] = fminf(red[0][1], red[w2][1]);
            red[0][2] = fminf(red[0][2], red[w2][2]);
            red[0][3] = fmaxf(red[0][3], red[w2][3]);
            red[0][4] = fmaxf(red[0][4], red[w2][4]);
            red[0][5] = fmaxf(red[0][5], red[w2][5]);
        }
        bbox[0] = red[0][0]; bbox[1] = red[0][1]; bbox[2] = red[0][2];
        bbox[3] = 16.0f / (fmaxf(red[0][3] - red[0][0], 1e-20f) * 1.000001f);
        bbox[4] = 16.0f / (fmaxf(red[0][4] - red[0][1], 1e-20f) * 1.000001f);
        bbox[5] = 16.0f / (fmaxf(red[0][5] - red[0][2], 1e-20f) * 1.000001f);
    }
}

__device__ __forceinline__ u32 mort(int cx, int cy, int cz) {
    u32 m = 0;
    #pragma unroll
    for (int b = 0; b < 4; ++b)
        m |= (((cx >> b) & 1) << (3 * b)) | (((cy >> b) & 1) << (3 * b + 1)) |
             (((cz >> b) & 1) << (3 * b + 2));
    return m;
}

__device__ __forceinline__ u32 cell_of(float x, float y, float z, const float* bb) {
    int cx = (int)((x - bb[0]) * bb[3]);
    int cy = (int)((y - bb[1]) * bb[4]);
    int cz = (int)((z - bb[2]) * bb[5]);
    cx = min(15, max(0, cx)); cy = min(15, max(0, cy)); cz = min(15, max(0, cz));
    return mort(cx, cy, cz);
}

// single-block Morton bucket sort: hist -> scan -> scatter (w = orig idx bits).
// Pads [NPTS..NPAD) = clones of the LAST SORTED point with idx sentinel 0xFFFF
// (inv16=0): real point beats clones on tie-break -> pads never win argmax;
// their md tracks the real point's md exactly (no cmax inflation).
__global__ void __launch_bounds__(1024) k_sort(const float* __restrict__ pos,
                                               const float* __restrict__ bbox,
                                               float4* __restrict__ spos) {
    __shared__ u32 hist[NCELL];
    __shared__ u32 wsum[16];
    const int tid = threadIdx.x, lane = tid & 63, wid = tid >> 6;
    float bb[6];
    #pragma unroll
    for (int j = 0; j < 6; ++j) bb[j] = bbox[j];
    for (int i = tid; i < NCELL; i += 1024) hist[i] = 0u;
    __syncthreads();
    for (int i = tid; i < NPTS; i += 1024) {
        float x = pos[3 * i], y = pos[3 * i + 1], z = pos[3 * i + 2];
        atomicAdd(&hist[cell_of(x, y, z, bb)], 1u);
    }
    __syncthreads();
    u32 h0 = hist[tid * 4], h1 = hist[tid * 4 + 1], h2 = hist[tid * 4 + 2], h3 = hist[tid * 4 + 3];
    u32 ts = h0 + h1 + h2 + h3;
    u32 sc = ts;
    #pragma unroll
    for (int o = 1; o < 64; o <<= 1) { u32 n = __shfl_up(sc, o); if (lane >= o) sc += n; }
    if (lane == 63) wsum[wid] = sc;
    __syncthreads();
    u32 woff = 0;
    for (int w2 = 0; w2 < wid; ++w2) woff += wsum[w2];
    u32 excl = woff + sc - ts;
    hist[tid * 4 + 0] = excl;
    hist[tid * 4 + 1] = excl + h0;
    hist[tid * 4 + 2] = excl + h0 + h1;
    hist[tid * 4 + 3] = excl + h0 + h1 + h2;
    __syncthreads();
    for (int i = tid; i < NPTS; i += 1024) {
        float x = pos[3 * i], y = pos[3 * i + 1], z = pos[3 * i + 2];
        u32 dst = atomicAdd(&hist[cell_of(x, y, z, bb)], 1u);
        spos[dst] = make_float4(x, y, z, __uint_as_float((u32)i));
    }
    __syncthreads();
    if (tid < NPAD - NPTS) {
        float4 lastp = spos[NPTS - 1];
        lastp.w = __uint_as_float(0xFFFFu);
        spos[NPTS + tid] = lastp;
    }
}

// Exact FPS v6: per-CHUNK (64-point) skip. Lane j owns chunk j of its wave:
// chunk bbox (6 regs), cmax (chunk max md), cached best (key,xyz). Per iter:
// lane-parallel skip test -> ballot -> statically-unrolled scan of active
// chunks only (j compile-time => md_r/lmd statically indexed, no scratch).
// Skip: lb*(1-1e-6) >= cmax => provably no md in chunk changes => caches exact.
// key = (md_bits<<32)|(0xFFFF-idx): u64-max == first-index argmax (jnp.argmax).
__global__ void __launch_bounds__(1024) k_fps6(const float4* __restrict__ spos,
                                               const float* __restrict__ pos,
                                               int* __restrict__ ids) {
    const int tid = threadIdx.x, lane = tid & 63, wid = tid >> 6;
    const int wbase = wid * WPW;
    __shared__ float lmd[1024 * MDS];       // 151552 B
    __shared__ u64 wkey[16];
    __shared__ float wpx[16], wpy[16], wpz[16];
    __shared__ float cs[4];
    float md_r[MDR];
    // per-lane chunk-owner state (lane j owns chunk j; lanes >= NCH own none)
    float cbxn = 3.4e38f, cbyn = 3.4e38f, cbzn = 3.4e38f;
    float cbxm = -3.4e38f, cbym = -3.4e38f, cbzm = -3.4e38f;
    float cmax = 0.0f;          // lanes >= NCH stay 0 -> never active
    u64 bk = 0ull;
    float bxr = 0.f, byr = 0.f, bzr = 0.f;
    // init: md = BIG; per-chunk bbox via per-j wave reduce, stored to lane j
    #pragma unroll
    for (int j = 0; j < NCH; ++j) {
        float4 s = spos[wbase + j * 64 + lane];
        if (j < MDR) md_r[j] = 1e10f; else lmd[tid * MDS + (j - MDR)] = 1e10f;
        float xn = s.x, xm = s.x, yn = s.y, ym = s.y, zn = s.z, zm = s.z;
        #pragma unroll
        for (int o = 32; o >= 1; o >>= 1) {
            xn = fminf(xn, __shfl_xor(xn, o)); xm = fmaxf(xm, __shfl_xor(xm, o));
            yn = fminf(yn, __shfl_xor(yn, o)); ym = fmaxf(ym, __shfl_xor(ym, o));
            zn = fminf(zn, __shfl_xor(zn, o)); zm = fmaxf(zm, __shfl_xor(zm, o));
        }
        if (lane == j) {
            cbxn = xn; cbxm = xm; cbyn = yn; cbym = ym; cbzn = zn; cbzm = zm;
            cmax = 1e10f;       // force first scan of every chunk
        }
    }
    float cx = pos[0], cy = pos[1], cz = pos[2];   // seed: original point 0
    if (tid == 0) ids[0] = 0;
    for (int it = 0; it < NITER; ++it) {
        // lane-parallel skip test: lane j tests chunk j
        float ddx = fmaxf(0.0f, fmaxf(cbxn - cx, cx - cbxm));
        float ddy = fmaxf(0.0f, fmaxf(cbyn - cy, cy - cbym));
        float ddz = fmaxf(0.0f, fmaxf(cbzn - cz, cz - cbzm));
        float lb = (ddx * ddx + ddy * ddy + ddz * ddz) * 0.999999f;
        u64 amask = __ballot(lb < cmax);
        if (amask) {
            #pragma unroll
            for (int j = 0; j < NCH; ++j) {
                if ((amask >> j) & 1) {     // wave-uniform, j compile-time
                    float4 s = spos[wbase + j * 64 + lane];
                    float dx = __fsub_rn(s.x, cx), dy = __fsub_rn(s.y, cy), dz = __fsub_rn(s.z, cz);
                    float d = __fadd_rn(__fadd_rn(__fmul_rn(dx, dx), __fmul_rn(dy, dy)),
                                        __fmul_rn(dz, dz));
                    float mold = (j < MDR) ? md_r[j] : lmd[tid * MDS + (j - MDR)];
                    float m = fminf(mold, d);
                    if (j < MDR) md_r[j] = m; else lmd[tid * MDS + (j - MDR)] = m;
                    u64 k = ((u64)__float_as_uint(m) << 32) |
                            (u64)(0xFFFFu - (u32)__float_as_uint(s.w));
                    int kl = lane;
                    #pragma unroll
                    for (int o = 32; o >= 1; o >>= 1) {
                        u64 ov = __shfl_xor(k, o);
                        int ol = __shfl_xor(kl, o);
                        if (ov > k) { k = ov; kl = ol; }
                    }
                    float wx = __shfl(s.x, kl), wy = __shfl(s.y, kl), wz = __shfl(s.z, kl);
                    if (lane == j) {
                        bk = k; cmax = __uint_as_float((u32)(k >> 32));
                        bxr = wx; byr = wy; bzr = wz;
                    }
                }
            }
            // wave best over chunk owners (cached bk for skipped chunks is exact)
            u64 kv = bk; int kl2 = lane;
            #pragma unroll
            for (int o = 32; o >= 1; o >>= 1) {
                u64 ov = __shfl_xor(kv, o);
                int ol = __shfl_xor(kl2, o);
                if (ov > kv) { kv = ov; kl2 = ol; }
            }
            float wx = __shfl(bxr, kl2), wy = __shfl(byr, kl2), wz = __shfl(bzr, kl2);
            if (lane == 0) { wkey[wid] = kv; wpx[wid] = wx; wpy[wid] = wy; wpz[wid] = wz; }
        }
        __syncthreads();
        // Phase B: wave 0 reduces 16 wave keys, carries wave index
        if (wid == 0) {
            u64 v = (lane < 16) ? wkey[lane] : 0ull;
            int vw = lane;
            #pragma unroll
            for (int o = 32; o >= 1; o >>= 1) {
                u64 ov = __shfl_xor(v, o);
                int ow = __shfl_xor(vw, o);
                if (ov > v) { v = ov; vw = ow; }
            }
            if (lane == 0) {
                ids[it + 1] = 0xFFFF - (int)(v & 0xFFFFull);
                cs[0] = wpx[vw]; cs[1] = wpy[vw]; cs[2] = wpz[vw];
            }
        }
        __syncthreads();
        cx = cs[0]; cy = cs[1]; cz = cs[2];
    }
}

// sub_pos + sub_batch outputs
__global__ void k_subs(const float* __restrict__ pos, const int* __restrict__ batch,
                       const int* __restrict__ ids, float* __restrict__ out) {
    int m = blockIdx.x * blockDim.x + threadIdx.x;
    if (m < MCL) {
        int id = ids[m];
        out[OUT_POS + m * 3 + 0] = pos[id * 3 + 0];
        out[OUT_POS + m * 3 + 1] = pos[id * 3 + 1];
        out[OUT_POS + m * 3 + 2] = pos[id * 3 + 2];
        out[OUT_BATCH + m] = (float)batch[id];  // zeros in this problem
    }
}

__device__ __forceinline__ u32 f2sort(float d) {
    u32 u = __float_as_uint(d);
    return (u & 0x80000000u) ? ~u : (u | 0x80000000u);
}

// per-(query-block, chunk) partial top-8 by (d, idx) lex key
__global__ void __launch_bounds__(256) k_knn(const float4* __restrict__ posf4,
                                             const int* __restrict__ ids,
                                             u64* __restrict__ cand) {
    __shared__ float4 tile[KTILE];
    const int bid = blockIdx.x, tid = threadIdx.x;
    const int qb = bid % QBLK, chunk = bid / QBLK;
    const int q = qb * 256 + tid;
    const bool act = q < MCL;
    float qx = 0.f, qy = 0.f, qz = 0.f, qq = 0.f;
    if (act) { float4 p = posf4[ids[q]]; qx = p.x; qy = p.y; qz = p.z; qq = p.w; }
    u64 r[8];
    #pragma unroll
    for (int j = 0; j < 8; ++j) r[j] = ~0ull;
    const int base0 = chunk * CPTS;
    for (int t = 0; t < NTILE; ++t) {
        __syncthreads();
        if (tid < KTILE) tile[tid] = posf4[base0 + t * KTILE + tid];
        __syncthreads();
        if (act) {
            for (int p = 0; p < KTILE; ++p) {
                float4 f = tile[p];
                // BLAS sgemm K=3 rounding: c=rn(qx*px); c=fma(qy,py,c); c=fma(qz,pz,c)
                float c = __fmul_rn(qx, f.x);
                c = fmaf(qy, f.y, c);
                c = fmaf(qz, f.z, c);
                float d = __fadd_rn(__fsub_rn(qq, __fmul_rn(2.0f, c)), f.w);
                u64 key = ((u64)f2sort(d) << 32) | (u32)(base0 + t * KTILE + p);
                if (key < r[7]) {
                    r[7] = key;
                    #pragma unroll
                    for (int jj = 7; jj >= 1; --jj) {
                        if (r[jj] < r[jj - 1]) { u64 tk = r[jj]; r[jj] = r[jj - 1]; r[jj - 1] = tk; }
                    }
                }
            }
        }
    }
    if (act) {
        #pragma unroll
        for (int j = 0; j < 8; ++j) cand[(size_t)q * 32 + chunk * 8 + j] = r[j];
    }
}

__global__ void k_merge(const u64* __restrict__ cand, int* __restrict__ col) {
    int q = blockIdx.x * blockDim.x + threadIdx.x;
    if (q >= MCL) return;
    u64 r[8];
    #pragma unroll
    for (int j = 0; j < 8; ++j) r[j] = ~0ull;
    for (int k = 0; k < 32; ++k) {
        u64 key = cand[(size_t)q * 32 + k];
        if (key < r[7]) {
            r[7] = key;
            #pragma unroll
            for (int jj = 7; jj >= 1; --jj) {
                if (r[jj] < r[jj - 1]) { u64 tk = r[jj]; r[jj] = r[jj - 1]; r[jj - 1] = tk; }
            }
        }
    }
    #pragma unroll
    for (int j = 0; j < 8; ++j) col[q * 8 + j] = (int)(r[j] & 0xFFFFFFFFull);
}

// Linear(64->128) per-channel sum / sumsq partials (64 rows per block)
__global__ void __launch_bounds__(256) k_linstats(const float* __restrict__ x,
                                                  const float* __restrict__ w,
                                                  const float* __restrict__ b,
                                                  float* __restrict__ psum,
                                                  float* __restrict__ psq) {
    __shared__ float xs[64 * 65];
    __shared__ float ws[128 * 65];
    const int bid = blockIdx.x, tid = threadIdx.x;
    const int row0 = bid * 64;
    for (int idx = tid; idx < 64 * 64; idx += 256) {
        int r = idx >> 6, j = idx & 63;
        int gr = row0 + r;
        xs[r * 65 + j] = (gr < NPTS) ? x[gr * 64 + j] : 0.0f;
    }
    for (int idx = tid; idx < 128 * 64; idx += 256) {
        int c = idx >> 6, j = idx & 63;
        ws[c * 65 + j] = w[idx];
    }
    __syncthreads();
    const int ch = tid & 127, grp = tid >> 7;
    const float lb = b[ch];
    float s = 0.f, sq = 0.f;
    for (int rr = 0; rr < 32; ++rr) {
        int r = grp * 32 + rr;
        float acc = lb;
        #pragma unroll 8
        for (int j = 0; j < 64; ++j) acc = fmaf(xs[r * 65 + j], ws[ch * 65 + j], acc);
        if (row0 + r < NPTS) { s += acc; sq = fmaf(acc, acc, sq); }
    }
    __syncthreads();
    float* red = xs;  // reuse
    red[grp * 128 + ch] = s;
    red[256 + grp * 128 + ch] = sq;
    __syncthreads();
    if (grp == 0) {
        psum[bid * 128 + ch] = red[ch] + red[128 + ch];
        psq[bid * 128 + ch] = red[256 + ch] + red[256 + 128 + ch];
    }
}

// mean/var -> per-channel affine (alpha, beta); folds GraphNorm
__global__ void k_finalize(const float* __restrict__ psum, const float* __restrict__ psq,
                           const float* __restrict__ gnw, const float* __restrict__ gnb,
                           const float* __restrict__ gms, float* __restrict__ ab) {
    int ch = threadIdx.x;  // 128 threads
    float s = 0.f, q = 0.f;
    for (int bk = 0; bk < RB; ++bk) { s += psum[bk * 128 + ch]; q += psq[bk * 128 + ch]; }
    float m = s / (float)NPTS;
    float e2 = q / (float)NPTS;
    float msc = gms[ch];
    float mm = msc * m;
    float var = e2 - 2.0f * mm * m + mm * mm;
    float inv = rsqrtf(var + 1e-5f);
    float a = inv * gnw[ch];
    ab[ch] = a;
    ab[128 + ch] = gnb[ch] - mm * a;
}

// recompute h rows for the 8 neighbors, max/min, affine+relu, write out
__global__ void __launch_bounds__(128) k_gather(const float* __restrict__ x,
                                                const float* __restrict__ w,
                                                const float* __restrict__ b,
                                                const int* __restrict__ col,
                                                const float* __restrict__ ab,
                                                float* __restrict__ out) {
    __shared__ float xs[8 * 64];
    __shared__ float ws[128 * 65];
    __shared__ int cl[8];
    const int m = blockIdx.x, tid = threadIdx.x;
    if (tid < 8) cl[tid] = col[m * 8 + tid];
    __syncthreads();
    for (int idx = tid; idx < 512; idx += 128) {
        int r = idx >> 6, j = idx & 63;
        xs[idx] = x[cl[r] * 64 + j];
    }
    for (int idx = tid; idx < 128 * 64; idx += 128) {
        int c = idx >> 6, j = idx & 63;
        ws[c * 65 + j] = w[idx];
    }
    __syncthreads();
    const int ch = tid;
    const float lb = b[ch];
    float hmax = -3.402823466e38f, hmin = 3.402823466e38f;
    #pragma unroll
    for (int r = 0; r < 8; ++r) {
        float acc = lb;
        #pragma unroll 8
        for (int j = 0; j < 64; ++j) acc = fmaf(xs[r * 64 + j], ws[ch * 65 + j], acc);
        hmax = fmaxf(hmax, acc);
        hmin = fminf(hmin, acc);
    }
    float a = ab[ch], be = ab[128 + ch];
    float v = (a >= 0.0f) ? hmax : hmin;   // max/affine commute per sign
    out[m * OUTC + ch] = fmaxf(0.0f, fmaf(a, v, be));
}

extern "C" void kernel_launch(void* const* d_in, const int* in_sizes, int n_in,
                              void* d_out, int out_size, void* d_ws, size_t ws_size,
                              hipStream_t stream) {
    const float* x     = (const float*)d_in[0];
    const float* pos   = (const float*)d_in[1];
    const int*   batch = (const int*)d_in[2];
    const float* lin_w = (const float*)d_in[3];
    const float* lin_b = (const float*)d_in[4];
    const float* gnw   = (const float*)d_in[5];
    const float* gnb   = (const float*)d_in[6];
    const float* gms   = (const float*)d_in[7];
    float* out = (float*)d_out;

    if (ws_size < (size_t)WS_TOTAL) return;  // fail loudly via wrong output

    char* ws = (char*)d_ws;
    int*    ids   = (int*)(ws + WS_IDS);
    float*  bbox  = (float*)(ws + WS_BBOX);
    float4* posf4 = (float4*)(ws + WS_POSF4);
    float4* spos  = (float4*)(ws + WS_SPOS);
    u64*    cand  = (u64*)(ws + WS_CAND);
    int*    col   = (int*)(ws + WS_COL);
    float*  psum  = (float*)(ws + WS_PSUM);
    float*  psq   = (float*)(ws + WS_PSQ);
    float*  ab    = (float*)(ws + WS_AB);

    k_prep<<<196, 256, 0, stream>>>(pos, posf4);
    k_bbox<<<1, 1024, 0, stream>>>(pos, bbox);
    k_sort<<<1, 1024, 0, stream>>>(pos, bbox, spos);
    k_fps6<<<1, 1024, 0, stream>>>(spos, pos, ids);
    k_subs<<<QBLK, 256, 0, stream>>>(pos, batch, ids, out);
    k_knn<<<QBLK * KCH, 256, 0, stream>>>(posf4, ids, cand);
    k_merge<<<QBLK, 256, 0, stream>>>(cand, col);
    k_linstats<<<RB, 256, 0, stream>>>(x, lin_w, lin_b, psum, psq);
    k_finalize<<<1, 128, 0, stream>>>(psum, psq, gnw, gnb, gms, ab);
    k_gather<<<MCL, 128, 0, stream>>>(x, lin_w, lin_b, col, ab, out);
}

// Round 11
// 43395.041 us; speedup vs baseline: 1.7746x; 1.1313x over previous
//
#include <hip/hip_runtime.h>
#include <stdint.h>

typedef unsigned long long u64;
typedef uint32_t u32;

#define NPTS 50000
#define MCL  8334          // ceil(50000/6)
#define NITER 8333         // FPS steps after seed
#define OUTC 128
#define WPW  3136          // points per wave (64 lanes * 49)
#define NCH  49            // chunks per wave (chunk j = 64 consecutive points)
#define NPAD (1024 * NCH)  // 50176
#define KCH 4              // knn N-chunks
#define CPTS 12500         // points per chunk
#define KTILE 250
#define NTILE 50
#define QBLK 33            // ceil(MCL/256)
#define RB 782             // ceil(NPTS/64) row-blocks for stats
#define NCELL 4096         // 16^3 Morton cells

// ---- ws byte offsets (total ~5.04 MB) ----
#define WS_IDS   0u            // 8448 i32
#define WS_BBOX  33792u        // 8 f32 (min xyz, scale xyz)
#define WS_POSF4 33824u        // 50000 float4 (orig order, w=||p||^2)  -> for KNN
#define WS_SPOS  833824u       // 50176 float4 (sorted, w=orig idx bits) -> for FPS
#define WS_MD    1636640u      // 50176 f32 (per-point min-dist, L2-resident)
#define WS_CAND  1837344u      // 8334*32 u64
#define WS_COL   3970848u      // 8334*8 i32
#define WS_PSUM  4237536u      // 782*128 f32
#define WS_PSQ   4637920u      // 782*128 f32
#define WS_AB    5038304u      // alpha[128], beta[128]
#define WS_TOTAL 5039328u

#define OUT_POS   (MCL * OUTC)            // 1066752
#define OUT_BATCH (OUT_POS + MCL * 3)     // 1091754

// pack pos + precomputed ||p||^2 (exact np order: (x*x+y*y)+z*z, no FMA)
__global__ void k_prep(const float* __restrict__ pos, float4* __restrict__ posf4) {
    int i = blockIdx.x * blockDim.x + threadIdx.x;
    if (i < NPTS) {
        float x = pos[3 * i], y = pos[3 * i + 1], z = pos[3 * i + 2];
        float pp = __fadd_rn(__fadd_rn(__fmul_rn(x, x), __fmul_rn(y, y)), __fmul_rn(z, z));
        posf4[i] = make_float4(x, y, z, pp);
    }
}

// global bbox -> min + scale (perf-only; any grouping is exact)
__global__ void __launch_bounds__(1024) k_bbox(const float* __restrict__ pos,
                                               float* __restrict__ bbox) {
    __shared__ float red[16][6];
    const int tid = threadIdx.x, lane = tid & 63, wid = tid >> 6;
    float mnx = 3.4e38f, mny = 3.4e38f, mnz = 3.4e38f;
    float mxx = -3.4e38f, mxy = -3.4e38f, mxz = -3.4e38f;
    for (int i = tid; i < NPTS; i += 1024) {
        float x = pos[3 * i], y = pos[3 * i + 1], z = pos[3 * i + 2];
        mnx = fminf(mnx, x); mxx = fmaxf(mxx, x);
        mny = fminf(mny, y); mxy = fmaxf(mxy, y);
        mnz = fminf(mnz, z); mxz = fmaxf(mxz, z);
    }
    #pragma unroll
    for (int o = 32; o >= 1; o >>= 1) {
        mnx = fminf(mnx, __shfl_xor(mnx, o)); mxx = fmaxf(mxx, __shfl_xor(mxx, o));
        mny = fminf(mny, __shfl_xor(mny, o)); mxy = fmaxf(mxy, __shfl_xor(mxy, o));
        mnz = fminf(mnz, __shfl_xor(mnz, o)); mxz = fmaxf(mxz, __shfl_xor(mxz, o));
    }
    if (lane == 0) {
        red[wid][0] = mnx; red[wid][1] = mny; red[wid][2] = mnz;
        red[wid][3] = mxx; red[wid][4] = mxy; red[wid][5] = mxz;
    }
    __syncthreads();
    if (tid == 0) {
        for (int w2 = 1; w2 < 16; ++w2) {
            red[0][0] = fminf(red[0][0], red[w2][0]);
            red[0][1] = fminf(red[0][1], red[w2][1]);
            red[0][2] = fminf(red[0][2], red[w2][2]);
            red[0][3] = fmaxf(red[0][3], red[w2][3]);
            red[0][4] = fmaxf(red[0][4], red[w2][4]);
            red[0][5] = fmaxf(red[0][5], red[w2][5]);
        }
        bbox[0] = red[0][0]; bbox[1] = red[0][1]; bbox[2] = red[0][2];
        bbox[3] = 16.0f / (fmaxf(red[0][3] - red[0][0], 1e-20f) * 1.000001f);
        bbox[4] = 16.0f / (fmaxf(red[0][4] - red[0][1], 1e-20f) * 1.000001f);
        bbox[5] = 16.0f / (fmaxf(red[0][5] - red[0][2], 1e-20f) * 1.000001f);
    }
}

__device__ __forceinline__ u32 mort(int cx, int cy, int cz) {
    u32 m = 0;
    #pragma unroll
    for (int b = 0; b < 4; ++b)
        m |= (((cx >> b) & 1) << (3 * b)) | (((cy >> b) & 1) << (3 * b + 1)) |
             (((cz >> b) & 1) << (3 * b + 2));
    return m;
}

__device__ __forceinline__ u32 cell_of(float x, float y, float z, const float* bb) {
    int cx = (int)((x - bb[0]) * bb[3]);
    int cy = (int)((y - bb[1]) * bb[4]);
    int cz = (int)((z - bb[2]) * bb[5]);
    cx = min(15, max(0, cx)); cy = min(15, max(0, cy)); cz = min(15, max(0, cz));
    return mort(cx, cy, cz);
}

// single-block Morton bucket sort: hist -> scan -> scatter (w = orig idx bits).
// Pads [NPTS..NPAD) = clones of the LAST SORTED point with idx sentinel 0xFFFF
// (inv16=0): real point beats clones on tie-break -> pads never win argmax;
// their md tracks the real point's md exactly (no cmax inflation).
__global__ void __launch_bounds__(1024) k_sort(const float* __restrict__ pos,
                                               const float* __restrict__ bbox,
                                               float4* __restrict__ spos) {
    __shared__ u32 hist[NCELL];
    __shared__ u32 wsum[16];
    const int tid = threadIdx.x, lane = tid & 63, wid = tid >> 6;
    float bb[6];
    #pragma unroll
    for (int j = 0; j < 6; ++j) bb[j] = bbox[j];
    for (int i = tid; i < NCELL; i += 1024) hist[i] = 0u;
    __syncthreads();
    for (int i = tid; i < NPTS; i += 1024) {
        float x = pos[3 * i], y = pos[3 * i + 1], z = pos[3 * i + 2];
        atomicAdd(&hist[cell_of(x, y, z, bb)], 1u);
    }
    __syncthreads();
    u32 h0 = hist[tid * 4], h1 = hist[tid * 4 + 1], h2 = hist[tid * 4 + 2], h3 = hist[tid * 4 + 3];
    u32 ts = h0 + h1 + h2 + h3;
    u32 sc = ts;
    #pragma unroll
    for (int o = 1; o < 64; o <<= 1) { u32 n = __shfl_up(sc, o); if (lane >= o) sc += n; }
    if (lane == 63) wsum[wid] = sc;
    __syncthreads();
    u32 woff = 0;
    for (int w2 = 0; w2 < wid; ++w2) woff += wsum[w2];
    u32 excl = woff + sc - ts;
    hist[tid * 4 + 0] = excl;
    hist[tid * 4 + 1] = excl + h0;
    hist[tid * 4 + 2] = excl + h0 + h1;
    hist[tid * 4 + 3] = excl + h0 + h1 + h2;
    __syncthreads();
    for (int i = tid; i < NPTS; i += 1024) {
        float x = pos[3 * i], y = pos[3 * i + 1], z = pos[3 * i + 2];
        u32 dst = atomicAdd(&hist[cell_of(x, y, z, bb)], 1u);
        spos[dst] = make_float4(x, y, z, __uint_as_float((u32)i));
    }
    __syncthreads();
    if (tid < NPAD - NPTS) {
        float4 lastp = spos[NPTS - 1];
        lastp.w = __uint_as_float(0xFFFFu);
        spos[NPTS + tid] = lastp;
    }
}

// Exact FPS v7: per-chunk (64-pt) skip, DATA-driven chunk loop (ffsll over the
// ballot mask -> compact code, no I-cache thrash), md[] in global ws
// (L2-resident, coalesced, no reg/LDS indexing -> no scratch), ONE barrier per
// iteration via parity-double-buffered wave-best slots + redundant all-wave
// Phase B (4-level reduce within 16-lane groups).
// Skip: lb*(1-1e-6) >= cmax => provably no md in chunk changes => caches exact.
// key = (md_bits<<32)|(0xFFFF-idx): u64-max == first-index argmax (jnp.argmax).
__global__ void __launch_bounds__(1024) k_fps7(const float4* __restrict__ spos,
                                               const float* __restrict__ pos,
                                               float* __restrict__ md,
                                               int* __restrict__ ids) {
    const int tid = threadIdx.x, lane = tid & 63, wid = tid >> 6;
    const int wbase = wid * WPW;
    __shared__ u64 wkey[2][16];
    __shared__ float wpx[2][16], wpy[2][16], wpz[2][16];
    // per-lane chunk-owner state (lane j < NCH owns chunk j of this wave)
    float cbxn = 3.4e38f, cbyn = 3.4e38f, cbzn = 3.4e38f;
    float cbxm = -3.4e38f, cbym = -3.4e38f, cbzm = -3.4e38f;
    float cmax = 0.0f;          // lanes >= NCH stay 0 -> never active
    u64 bk = 0ull;              // cached per-chunk best key (owner lane)
    float bxr = 0.f, byr = 0.f, bzr = 0.f;
    u64 wbk = 0ull;             // cached wave best (uniform)
    float wbx = 0.f, wby = 0.f, wbz = 0.f;
    // init: wave-local md = BIG; per-chunk bbox reduced to owner lane j
    for (int j = 0; j < NCH; ++j) {
        int gi = wbase + j * 64 + lane;
        float4 s = spos[gi];
        md[gi] = 1e10f;
        float xn = s.x, xm = s.x, yn = s.y, ym = s.y, zn = s.z, zm = s.z;
        #pragma unroll
        for (int o = 32; o >= 1; o >>= 1) {
            xn = fminf(xn, __shfl_xor(xn, o)); xm = fmaxf(xm, __shfl_xor(xm, o));
            yn = fminf(yn, __shfl_xor(yn, o)); ym = fmaxf(ym, __shfl_xor(ym, o));
            zn = fminf(zn, __shfl_xor(zn, o)); zm = fmaxf(zm, __shfl_xor(zm, o));
        }
        if (lane == j) {
            cbxn = xn; cbxm = xm; cbyn = yn; cbym = ym; cbzn = zn; cbzm = zm;
            cmax = 1e10f;       // force first scan of every chunk
        }
    }
    float cx = pos[0], cy = pos[1], cz = pos[2];   // seed: original point 0
    if (tid == 0) ids[0] = 0;
    for (int it = 0; it < NITER; ++it) {
        const int p = it & 1;
        // lane-parallel skip test: lane j tests chunk j
        float ddx = fmaxf(0.0f, fmaxf(cbxn - cx, cx - cbxm));
        float ddy = fmaxf(0.0f, fmaxf(cbyn - cy, cy - cbym));
        float ddz = fmaxf(0.0f, fmaxf(cbzn - cz, cz - cbzm));
        float lb = (ddx * ddx + ddy * ddy + ddz * ddz) * 0.999999f;
        u64 amask = __ballot(lb < cmax);
        if (amask) {
            u64 mm = amask;
            while (mm) {
                int j = __ffsll(mm) - 1;    // runtime j: md is global -> fine
                mm &= mm - 1;
                int gi = wbase + j * 64 + lane;
                float4 s = spos[gi];
                // exact np arithmetic: rn sub/mul/add, no contraction
                float dx = __fsub_rn(s.x, cx), dy = __fsub_rn(s.y, cy), dz = __fsub_rn(s.z, cz);
                float d = __fadd_rn(__fadd_rn(__fmul_rn(dx, dx), __fmul_rn(dy, dy)),
                                    __fmul_rn(dz, dz));
                float m = fminf(md[gi], d);
                md[gi] = m;
                u64 k = ((u64)__float_as_uint(m) << 32) |
                        (u64)(0xFFFFu - (u32)__float_as_uint(s.w));
                int kl = lane;
                #pragma unroll
                for (int o = 32; o >= 1; o >>= 1) {
                    u64 ov = __shfl_xor(k, o);
                    int ol = __shfl_xor(kl, o);
                    if (ov > k) { k = ov; kl = ol; }
                }
                float wx = __shfl(s.x, kl), wy = __shfl(s.y, kl), wz = __shfl(s.z, kl);
                if (lane == j) {
                    bk = k; cmax = __uint_as_float((u32)(k >> 32));
                    bxr = wx; byr = wy; bzr = wz;
                }
            }
            // recompute wave best from all owner-lane caches
            u64 kv = bk; int kl2 = lane;
            #pragma unroll
            for (int o = 32; o >= 1; o >>= 1) {
                u64 ov = __shfl_xor(kv, o);
                int ol = __shfl_xor(kl2, o);
                if (ov > kv) { kv = ov; kl2 = ol; }
            }
            wbk = kv;
            wbx = __shfl(bxr, kl2); wby = __shfl(byr, kl2); wbz = __shfl(bzr, kl2);
        }
        if (lane == 0) {
            wkey[p][wid] = wbk;
            wpx[p][wid] = wbx; wpy[p][wid] = wby; wpz[p][wid] = wbz;
        }
        __syncthreads();
        // Phase B (all waves, redundant): 4-level reduce within 16-lane groups
        u64 v = wkey[p][lane & 15];
        int vw = lane & 15;
        #pragma unroll
        for (int o = 8; o >= 1; o >>= 1) {
            u64 ov = __shfl_xor(v, o);
            int ow = __shfl_xor(vw, o);
            if (ov > v) { v = ov; vw = ow; }
        }
        cx = wpx[p][vw]; cy = wpy[p][vw]; cz = wpz[p][vw];
        if (tid == 0) ids[it + 1] = 0xFFFF - (int)(v & 0xFFFFull);
    }
}

// sub_pos + sub_batch outputs
__global__ void k_subs(const float* __restrict__ pos, const int* __restrict__ batch,
                       const int* __restrict__ ids, float* __restrict__ out) {
    int m = blockIdx.x * blockDim.x + threadIdx.x;
    if (m < MCL) {
        int id = ids[m];
        out[OUT_POS + m * 3 + 0] = pos[id * 3 + 0];
        out[OUT_POS + m * 3 + 1] = pos[id * 3 + 1];
        out[OUT_POS + m * 3 + 2] = pos[id * 3 + 2];
        out[OUT_BATCH + m] = (float)batch[id];  // zeros in this problem
    }
}

__device__ __forceinline__ u32 f2sort(float d) {
    u32 u = __float_as_uint(d);
    return (u & 0x80000000u) ? ~u : (u | 0x80000000u);
}

// per-(query-block, chunk) partial top-8 by (d, idx) lex key
__global__ void __launch_bounds__(256) k_knn(const float4* __restrict__ posf4,
                                             const int* __restrict__ ids,
                                             u64* __restrict__ cand) {
    __shared__ float4 tile[KTILE];
    const int bid = blockIdx.x, tid = threadIdx.x;
    const int qb = bid % QBLK, chunk = bid / QBLK;
    const int q = qb * 256 + tid;
    const bool act = q < MCL;
    float qx = 0.f, qy = 0.f, qz = 0.f, qq = 0.f;
    if (act) { float4 p = posf4[ids[q]]; qx = p.x; qy = p.y; qz = p.z; qq = p.w; }
    u64 r[8];
    #pragma unroll
    for (int j = 0; j < 8; ++j) r[j] = ~0ull;
    const int base0 = chunk * CPTS;
    for (int t = 0; t < NTILE; ++t) {
        __syncthreads();
        if (tid < KTILE) tile[tid] = posf4[base0 + t * KTILE + tid];
        __syncthreads();
        if (act) {
            for (int p = 0; p < KTILE; ++p) {
                float4 f = tile[p];
                // BLAS sgemm K=3 rounding: c=rn(qx*px); c=fma(qy,py,c); c=fma(qz,pz,c)
                float c = __fmul_rn(qx, f.x);
                c = fmaf(qy, f.y, c);
                c = fmaf(qz, f.z, c);
                float d = __fadd_rn(__fsub_rn(qq, __fmul_rn(2.0f, c)), f.w);
                u64 key = ((u64)f2sort(d) << 32) | (u32)(base0 + t * KTILE + p);
                if (key < r[7]) {
                    r[7] = key;
                    #pragma unroll
                    for (int jj = 7; jj >= 1; --jj) {
                        if (r[jj] < r[jj - 1]) { u64 tk = r[jj]; r[jj] = r[jj - 1]; r[jj - 1] = tk; }
                    }
                }
            }
        }
    }
    if (act) {
        #pragma unroll
        for (int j = 0; j < 8; ++j) cand[(size_t)q * 32 + chunk * 8 + j] = r[j];
    }
}

__global__ void k_merge(const u64* __restrict__ cand, int* __restrict__ col) {
    int q = blockIdx.x * blockDim.x + threadIdx.x;
    if (q >= MCL) return;
    u64 r[8];
    #pragma unroll
    for (int j = 0; j < 8; ++j) r[j] = ~0ull;
    for (int k = 0; k < 32; ++k) {
        u64 key = cand[(size_t)q * 32 + k];
        if (key < r[7]) {
            r[7] = key;
            #pragma unroll
            for (int jj = 7; jj >= 1; --jj) {
                if (r[jj] < r[jj - 1]) { u64 tk = r[jj]; r[jj] = r[jj - 1]; r[jj - 1] = tk; }
            }
        }
    }
    #pragma unroll
    for (int j = 0; j < 8; ++j) col[q * 8 + j] = (int)(r[j] & 0xFFFFFFFFull);
}

// Linear(64->128) per-channel sum / sumsq partials (64 rows per block)
__global__ void __launch_bounds__(256) k_linstats(const float* __restrict__ x,
                                                  const float* __restrict__ w,
                                                  const float* __restrict__ b,
                                                  float* __restrict__ psum,
                                                  float* __restrict__ psq) {
    __shared__ float xs[64 * 65];
    __shared__ float ws[128 * 65];
    const int bid = blockIdx.x, tid = threadIdx.x;
    const int row0 = bid * 64;
    for (int idx = tid; idx < 64 * 64; idx += 256) {
        int r = idx >> 6, j = idx & 63;
        int gr = row0 + r;
        xs[r * 65 + j] = (gr < NPTS) ? x[gr * 64 + j] : 0.0f;
    }
    for (int idx = tid; idx < 128 * 64; idx += 256) {
        int c = idx >> 6, j = idx & 63;
        ws[c * 65 + j] = w[idx];
    }
    __syncthreads();
    const int ch = tid & 127, grp = tid >> 7;
    const float lb = b[ch];
    float s = 0.f, sq = 0.f;
    for (int rr = 0; rr < 32; ++rr) {
        int r = grp * 32 + rr;
        float acc = lb;
        #pragma unroll 8
        for (int j = 0; j < 64; ++j) acc = fmaf(xs[r * 65 + j], ws[ch * 65 + j], acc);
        if (row0 + r < NPTS) { s += acc; sq = fmaf(acc, acc, sq); }
    }
    __syncthreads();
    float* red = xs;  // reuse
    red[grp * 128 + ch] = s;
    red[256 + grp * 128 + ch] = sq;
    __syncthreads();
    if (grp == 0) {
        psum[bid * 128 + ch] = red[ch] + red[128 + ch];
        psq[bid * 128 + ch] = red[256 + ch] + red[256 + 128 + ch];
    }
}

// mean/var -> per-channel affine (alpha, beta); folds GraphNorm
__global__ void k_finalize(const float* __restrict__ psum, const float* __restrict__ psq,
                           const float* __restrict__ gnw, const float* __restrict__ gnb,
                           const float* __restrict__ gms, float* __restrict__ ab) {
    int ch = threadIdx.x;  // 128 threads
    float s = 0.f, q = 0.f;
    for (int bk = 0; bk < RB; ++bk) { s += psum[bk * 128 + ch]; q += psq[bk * 128 + ch]; }
    float m = s / (float)NPTS;
    float e2 = q / (float)NPTS;
    float msc = gms[ch];
    float mm = msc * m;
    float var = e2 - 2.0f * mm * m + mm * mm;
    float inv = rsqrtf(var + 1e-5f);
    float a = inv * gnw[ch];
    ab[ch] = a;
    ab[128 + ch] = gnb[ch] - mm * a;
}

// recompute h rows for the 8 neighbors, max/min, affine+relu, write out
__global__ void __launch_bounds__(128) k_gather(const float* __restrict__ x,
                                                const float* __restrict__ w,
                                                const float* __restrict__ b,
                                                const int* __restrict__ col,
                                                const float* __restrict__ ab,
                                                float* __restrict__ out) {
    __shared__ float xs[8 * 64];
    __shared__ float ws[128 * 65];
    __shared__ int cl[8];
    const int m = blockIdx.x, tid = threadIdx.x;
    if (tid < 8) cl[tid] = col[m * 8 + tid];
    __syncthreads();
    for (int idx = tid; idx < 512; idx += 128) {
        int r = idx >> 6, j = idx & 63;
        xs[idx] = x[cl[r] * 64 + j];
    }
    for (int idx = tid; idx < 128 * 64; idx += 128) {
        int c = idx >> 6, j = idx & 63;
        ws[c * 65 + j] = w[idx];
    }
    __syncthreads();
    const int ch = tid;
    const float lb = b[ch];
    float hmax = -3.402823466e38f, hmin = 3.402823466e38f;
    #pragma unroll
    for (int r = 0; r < 8; ++r) {
        float acc = lb;
        #pragma unroll 8
        for (int j = 0; j < 64; ++j) acc = fmaf(xs[r * 64 + j], ws[ch * 65 + j], acc);
        hmax = fmaxf(hmax, acc);
        hmin = fminf(hmin, acc);
    }
    float a = ab[ch], be = ab[128 + ch];
    float v = (a >= 0.0f) ? hmax : hmin;   // max/affine commute per sign
    out[m * OUTC + ch] = fmaxf(0.0f, fmaf(a, v, be));
}

extern "C" void kernel_launch(void* const* d_in, const int* in_sizes, int n_in,
                              void* d_out, int out_size, void* d_ws, size_t ws_size,
                              hipStream_t stream) {
    const float* x     = (const float*)d_in[0];
    const float* pos   = (const float*)d_in[1];
    const int*   batch = (const int*)d_in[2];
    const float* lin_w = (const float*)d_in[3];
    const float* lin_b = (const float*)d_in[4];
    const float* gnw   = (const float*)d_in[5];
    const float* gnb   = (const float*)d_in[6];
    const float* gms   = (const float*)d_in[7];
    float* out = (float*)d_out;

    if (ws_size < (size_t)WS_TOTAL) return;  // fail loudly via wrong output

    char* ws = (char*)d_ws;
    int*    ids   = (int*)(ws + WS_IDS);
    float*  bbox  = (float*)(ws + WS_BBOX);
    float4* posf4 = (float4*)(ws + WS_POSF4);
    float4* spos  = (float4*)(ws + WS_SPOS);
    float*  mdbuf = (float*)(ws + WS_MD);
    u64*    cand  = (u64*)(ws + WS_CAND);
    int*    col   = (int*)(ws + WS_COL);
    float*  psum  = (float*)(ws + WS_PSUM);
    float*  psq   = (float*)(ws + WS_PSQ);
    float*  ab    = (float*)(ws + WS_AB);

    k_prep<<<196, 256, 0, stream>>>(pos, posf4);
    k_bbox<<<1, 1024, 0, stream>>>(pos, bbox);
    k_sort<<<1, 1024, 0, stream>>>(pos, bbox, spos);
    k_fps7<<<1, 1024, 0, stream>>>(spos, pos, mdbuf, ids);
    k_subs<<<QBLK, 256, 0, stream>>>(pos, batch, ids, out);
    k_knn<<<QBLK * KCH, 256, 0, stream>>>(posf4, ids, cand);
    k_merge<<<QBLK, 256, 0, stream>>>(cand, col);
    k_linstats<<<RB, 256, 0, stream>>>(x, lin_w, lin_b, psum, psq);
    k_finalize<<<1, 128, 0, stream>>>(psum, psq, gnw, gnb, gms, ab);
    k_gather<<<MCL, 128, 0, stream>>>(x, lin_w, lin_b, col, ab, out);
}